// Round 1
// baseline (331.328 us; speedup 1.0000x reference)
//
#include <hip/hip_runtime.h>

// Problem constants (fixed by setup_inputs)
constexpr int B = 4;
constexpr int N = 768;
constexpr int D = 16;           // per-node embedding dim
constexpr int E = 12288;        // edges per batch
constexpr int NN = N * N;       // 589824 pairs per batch
constexpr int PAIRS = B * NN;   // 2,359,296
// d_out layout (fp32, concatenated in return order):
//   [0, B*NN*2D)                      edge_embeddings
//   [B*NN*2D, B*NN*2D + B*NN)         logits
//   [.. + B*NN, .. + 2*B*NN)          truth
constexpr long long EE_FLOATS = (long long)PAIRS * 2 * D;  // 75,497,472

// K1: edge_embeddings. One thread per float4 (8 float4 per pair:
// q<4 -> emb[b,i] quarter q ; q>=4 -> emb[b,j] quarter q-4).
// Consecutive threads write consecutive 16B -> fully coalesced.
__global__ void ee_fill_kernel(const float4* __restrict__ emb4,
                               float4* __restrict__ out4, int total4) {
    int idx = blockIdx.x * blockDim.x + threadIdx.x;
    if (idx >= total4) return;
    int pair = idx >> 3;
    int q = idx & 7;
    int b = pair / NN;
    int rem = pair - b * NN;
    int i = rem / N;
    int j = rem - i * N;
    int node = (q < 4) ? i : j;
    out4[idx] = emb4[((b * N + node) << 2) + (q & 3)];
}

// K2: logits (masked dot with W + bias) and zero the truth region.
__global__ void logits_kernel(const float4* __restrict__ emb4,
                              const float* __restrict__ W,
                              const float* __restrict__ bias,
                              float* __restrict__ logits,
                              float* __restrict__ truth, int total) {
    int p = blockIdx.x * blockDim.x + threadIdx.x;
    if (p >= total) return;
    int b = p / NN;
    int rem = p - b * NN;
    int i = rem / N;
    int j = rem - i * N;
    const float4* ei = emb4 + ((b * N + i) << 2);
    const float4* ej = emb4 + ((b * N + j) << 2);
    float acc = 0.f;
    float diff = 0.f;
#pragma unroll
    for (int q = 0; q < 4; ++q) {
        float4 a = ei[q];
        float4 c = ej[q];
        const float* w1 = W + q * 4;       // weight for inter half
        const float* w2 = W + D + q * 4;   // weight for rep half
        acc += a.x * w1[0] + a.y * w1[1] + a.z * w1[2] + a.w * w1[3];
        acc += c.x * w2[0] + c.y * w2[1] + c.z * w2[2] + c.w * w2[3];
        diff += fabsf(a.x - c.x) + fabsf(a.y - c.y) +
                fabsf(a.z - c.z) + fabsf(a.w - c.w);
    }
    acc += bias[0];
    logits[p] = (diff != 0.f) ? acc : -10.0f;
    truth[p] = 0.0f;
}

// K3: scatter ground-truth edges. edges layout [B, 2, E]; duplicates are
// idempotent (plain store of 1.0).
__global__ void truth_scatter_kernel(const int* __restrict__ edges,
                                     float* __restrict__ truth) {
    int t = blockIdx.x * blockDim.x + threadIdx.x;
    if (t >= B * E) return;
    int b = t / E;
    int e = t - b * E;
    int src = edges[b * 2 * E + e];
    int dst = edges[b * 2 * E + E + e];
    truth[(long long)b * NN + src * N + dst] = 1.0f;
}

extern "C" void kernel_launch(void* const* d_in, const int* in_sizes, int n_in,
                              void* d_out, int out_size, void* d_ws, size_t ws_size,
                              hipStream_t stream) {
    const float4* emb4 = (const float4*)d_in[0];       // [B,N,D] fp32, D=16 -> 4 float4/row
    const int* edges = (const int*)d_in[1];            // [B,2,E] int
    const float* W = (const float*)d_in[2];            // [2D]
    const float* bias = (const float*)d_in[3];         // [1]

    float* out = (float*)d_out;
    float* ee = out;
    float* logits = out + EE_FLOATS;
    float* truth = out + EE_FLOATS + (long long)PAIRS;

    // K1: 18,874,368 float4 stores
    {
        int total4 = PAIRS * 8;
        int threads = 256;
        int blocks = (total4 + threads - 1) / threads;
        ee_fill_kernel<<<blocks, threads, 0, stream>>>(emb4, (float4*)ee, total4);
    }
    // K2: one thread per pair (also zeroes truth)
    {
        int threads = 256;
        int blocks = (PAIRS + threads - 1) / threads;
        logits_kernel<<<blocks, threads, 0, stream>>>(emb4, W, bias, logits, truth, PAIRS);
    }
    // K3: scatter edges into truth (after K2's zeroing; same stream => ordered)
    {
        int threads = 256;
        int blocks = (B * E + threads - 1) / threads;
        truth_scatter_kernel<<<blocks, threads, 0, stream>>>(edges, truth);
    }
}